// Round 1
// baseline (375.922 us; speedup 1.0000x reference)
//
#include <hip/hip_runtime.h>

// PointnetFPModule: three_nn (brute force, top-3 smallest d2) + three_interpolate.
// Shapes: B=8, N=8192, M=2048, C=256.  All fp32.
// unknown (B,N,3), known (B,M,3), known_feats (B,C,M) -> out (B,C,N)

#define BB 8
#define NN 8192
#define MM 2048
#define CC 256
#define EPSV 1e-8f
#define PTS 256   // unknown points per block

__global__ __launch_bounds__(PTS) void fp_interp_kernel(
    const float* __restrict__ unknown,
    const float* __restrict__ known,
    const float* __restrict__ feats,
    float* __restrict__ out)
{
    __shared__ float kxs[MM];
    __shared__ float kys[MM];
    __shared__ float kzs[MM];

    const int tilesPerBatch = NN / PTS;          // 32
    const int b    = blockIdx.x / tilesPerBatch;
    const int tile = blockIdx.x % tilesPerBatch;
    const int tid  = threadIdx.x;
    const int n    = tile * PTS + tid;

    // Stage known[b] into LDS (SoA). known is (B, M, 3) row-major.
    const float* kb = known + (size_t)b * MM * 3;
    for (int i = tid; i < MM; i += PTS) {
        kxs[i] = kb[i * 3 + 0];
        kys[i] = kb[i * 3 + 1];
        kzs[i] = kb[i * 3 + 2];
    }
    __syncthreads();

    const float* ub = unknown + ((size_t)b * NN + n) * 3;
    const float ux = ub[0], uy = ub[1], uz = ub[2];

    // Top-3 smallest squared distances; strict < keeps lowest index on ties
    // (matches jax.lax.top_k stability).
    float d0 = 1e30f, d1 = 1e30f, d2 = 1e30f;
    int   i0 = 0,     i1 = 0,     i2 = 0;

    #pragma unroll 4
    for (int m = 0; m < MM; ++m) {
        // Match numpy exactly: no FMA contraction, sum order (x^2 + y^2) + z^2.
        const float dx = ux - kxs[m];
        const float dy = uy - kys[m];
        const float dz = uz - kzs[m];
        const float d = __fadd_rn(__fadd_rn(__fmul_rn(dx, dx), __fmul_rn(dy, dy)),
                                  __fmul_rn(dz, dz));
        if (d < d2) {
            if (d < d1) {
                d2 = d1; i2 = i1;
                if (d < d0) { d1 = d0; i1 = i0; d0 = d; i0 = m; }
                else        { d1 = d;  i1 = m; }
            } else {
                d2 = d; i2 = m;
            }
        }
    }

    const float r0 = 1.0f / (d0 + EPSV);
    const float r1 = 1.0f / (d1 + EPSV);
    const float r2 = 1.0f / (d2 + EPSV);
    const float rs = r0 + r1 + r2;
    const float w0 = r0 / rs, w1 = r1 / rs, w2 = r2 / rs;

    // Interpolate: out[b][c][n] = w0*F[b][c][i0] + w1*F[b][c][i1] + w2*F[b][c][i2]
    const float* fb = feats + (size_t)b * CC * MM;
    float* ob = out + (size_t)b * CC * NN + (size_t)tile * PTS;

    #pragma unroll 4
    for (int c = 0; c < CC; ++c) {
        const float* fr = fb + (size_t)c * MM;
        ob[(size_t)c * NN + tid] = w0 * fr[i0] + w1 * fr[i1] + w2 * fr[i2];
    }
}

extern "C" void kernel_launch(void* const* d_in, const int* in_sizes, int n_in,
                              void* d_out, int out_size, void* d_ws, size_t ws_size,
                              hipStream_t stream) {
    const float* unknown = (const float*)d_in[0];
    const float* known   = (const float*)d_in[1];
    const float* feats   = (const float*)d_in[2];
    float* out = (float*)d_out;

    const int nBlocks = BB * (NN / PTS);  // 256
    fp_interp_kernel<<<nBlocks, PTS, 0, stream>>>(unknown, known, feats, out);
}

// Round 2
// 208.065 us; speedup vs baseline: 1.8068x; 1.8068x over previous
//
#include <hip/hip_runtime.h>

// PointnetFPModule: three_nn (brute force, top-3 smallest d2) + three_interpolate.
// Shapes: B=8, N=8192, M=2048, C=256.  All fp32.
// unknown (B,N,3), known (B,M,3), known_feats (B,C,M) -> out (B,C,N)
//
// R2: occupancy was the limit (11.7%, 1 wave/SIMD). Split each point's M-scan
// across NCH=4 threads (disjoint index chunks) + stable merge of partial top-3
// lists. Grid: 1024 blocks x 4 waves = 16 waves/CU.

#define BB 8
#define NN 8192
#define MM 2048
#define CC 256
#define EPSV 1e-8f
#define PTS 64          // unknown points per block
#define NCH 4           // scan chunks (threads per point)
#define CHUNK (MM/NCH)  // 512

__global__ __launch_bounds__(256) void fp_interp_kernel(
    const float* __restrict__ unknown,
    const float* __restrict__ known,
    const float* __restrict__ feats,
    float* __restrict__ out)
{
    __shared__ float kxs[MM];
    __shared__ float kys[MM];
    __shared__ float kzs[MM];
    __shared__ float pd[NCH][PTS][3];
    __shared__ int   pi[NCH][PTS][3];
    __shared__ float sw[3][PTS];
    __shared__ int   si[3][PTS];

    const int tilesPerBatch = NN / PTS;          // 128
    const int b    = blockIdx.x / tilesPerBatch;
    const int tile = blockIdx.x % tilesPerBatch;
    const int t    = threadIdx.x;
    const int p    = t & 63;    // point within tile (lane)
    const int g    = t >> 6;    // chunk / wave-group id (uniform per wave)
    const int n    = tile * PTS + p;

    // Stage known[b] into LDS (SoA). known is (B, M, 3) row-major.
    const float* kb = known + (size_t)b * MM * 3;
    for (int i = t; i < MM; i += 256) {
        kxs[i] = kb[i * 3 + 0];
        kys[i] = kb[i * 3 + 1];
        kzs[i] = kb[i * 3 + 2];
    }
    __syncthreads();

    const float* ub = unknown + ((size_t)b * NN + n) * 3;
    const float ux = ub[0], uy = ub[1], uz = ub[2];

    // Partial top-3 over this thread's chunk [g*CHUNK, (g+1)*CHUNK).
    // Strict < keeps lowest index on ties (matches jax.lax.top_k stability).
    float d0 = 1e30f, d1 = 1e30f, d2 = 1e30f;
    int   i0 = 0,     i1 = 0,     i2 = 0;

    const int mbeg = g * CHUNK, mend = mbeg + CHUNK;
    #pragma unroll 4
    for (int m = mbeg; m < mend; ++m) {
        // Match numpy exactly: no FMA contraction, sum order (x^2 + y^2) + z^2.
        const float dx = ux - kxs[m];
        const float dy = uy - kys[m];
        const float dz = uz - kzs[m];
        const float d = __fadd_rn(__fadd_rn(__fmul_rn(dx, dx), __fmul_rn(dy, dy)),
                                  __fmul_rn(dz, dz));
        if (d < d2) {
            if (d < d1) {
                d2 = d1; i2 = i1;
                if (d < d0) { d1 = d0; i1 = i0; d0 = d; i0 = m; }
                else        { d1 = d;  i1 = m; }
            } else {
                d2 = d; i2 = m;
            }
        }
    }

    pd[g][p][0] = d0; pd[g][p][1] = d1; pd[g][p][2] = d2;
    pi[g][p][0] = i0; pi[g][p][1] = i1; pi[g][p][2] = i2;
    __syncthreads();

    // Merge 4 sorted partial lists per point (one thread per point).
    // Insertion order = (chunk asc, rank asc) = index order for equal d,
    // so strict-< insertion reproduces the in-order full scan.
    if (t < PTS) {
        float e0 = 1e30f, e1 = 1e30f, e2 = 1e30f;
        int   j0 = 0,     j1 = 0,     j2 = 0;
        #pragma unroll
        for (int q = 0; q < NCH; ++q) {
            #pragma unroll
            for (int r = 0; r < 3; ++r) {
                const float d  = pd[q][t][r];
                const int   ii = pi[q][t][r];
                if (d < e2) {
                    if (d < e1) {
                        e2 = e1; j2 = j1;
                        if (d < e0) { e1 = e0; j1 = j0; e0 = d; j0 = ii; }
                        else        { e1 = d;  j1 = ii; }
                    } else {
                        e2 = d; j2 = ii;
                    }
                }
            }
        }
        const float r0 = 1.0f / (e0 + EPSV);
        const float r1 = 1.0f / (e1 + EPSV);
        const float r2 = 1.0f / (e2 + EPSV);
        const float rs = r0 + r1 + r2;
        sw[0][t] = r0 / rs; sw[1][t] = r1 / rs; sw[2][t] = r2 / rs;
        si[0][t] = j0;      si[1][t] = j1;      si[2][t] = j2;
    }
    __syncthreads();

    // Interpolate: out[b][c][n] = sum_k w_k * F[b][c][i_k].
    // Wave-group g handles channels c = g, g+4, ... (stores are 64-lane
    // contiguous 256B per channel row).
    const float w0 = sw[0][p], w1 = sw[1][p], w2 = sw[2][p];
    const int   j0 = si[0][p], j1 = si[1][p], j2 = si[2][p];
    const float* fb = feats + (size_t)b * CC * MM;
    float* ob = out + (size_t)b * CC * NN + (size_t)tile * PTS;

    #pragma unroll 4
    for (int c = g; c < CC; c += NCH) {
        const float* fr = fb + (size_t)c * MM;
        ob[(size_t)c * NN + p] = w0 * fr[j0] + w1 * fr[j1] + w2 * fr[j2];
    }
}

extern "C" void kernel_launch(void* const* d_in, const int* in_sizes, int n_in,
                              void* d_out, int out_size, void* d_ws, size_t ws_size,
                              hipStream_t stream) {
    const float* unknown = (const float*)d_in[0];
    const float* known   = (const float*)d_in[1];
    const float* feats   = (const float*)d_in[2];
    float* out = (float*)d_out;

    const int nBlocks = BB * (NN / PTS);  // 1024
    fp_interp_kernel<<<nBlocks, 256, 0, stream>>>(unknown, known, feats, out);
}

// Round 3
// 194.383 us; speedup vs baseline: 1.9339x; 1.0704x over previous
//
#include <hip/hip_runtime.h>

// PointnetFPModule: three_nn (brute force, top-3 smallest d2) + three_interpolate.
// Shapes: B=8, N=8192, M=2048, C=256.  All fp32.
// unknown (B,N,3), known (B,M,3), known_feats (B,C,M) -> out (B,C,N)
//
// R3: scan was LDS-issue-bound (3 ds_read_b32 per pair; per-CU LDS pipe 4x
// oversubscribed -> VALUBusy 37%). Fix: ds_read_b128 (float4, 4 m per read)
// + 2 points per thread so each staged quad serves 2 points. 512-thread
// blocks, 8 wave-uniform chunks, 128 points/block, grid 512.

#define BB 8
#define NN 8192
#define MM 2048
#define CC 256
#define EPSV 1e-8f
#define PTS 128          // points per block (64 lanes x 2 points/thread)
#define NTH 512          // threads per block = 8 waves
#define NCH 8            // chunks = waves (chunk id wave-uniform!)
#define CHUNK (MM/NCH)   // 256

// Stable top-3 insert: strict < keeps lowest index on ties; candidates are
// presented in ascending-index order, so this matches jax.lax.top_k.
#define INS(dd, mi, D0,I0,D1,I1,D2,I2) \
    if ((dd) < D2) { \
        if ((dd) < D1) { D2 = D1; I2 = I1; \
            if ((dd) < D0) { D1 = D0; I1 = I0; D0 = (dd); I0 = (mi); } \
            else           { D1 = (dd); I1 = (mi); } \
        } else { D2 = (dd); I2 = (mi); } }

// One known point vs both unknown points. Match numpy exactly: no FMA
// contraction, sum order (x^2 + y^2) + z^2.
#define STEP(KX,KY,KZ,MI) { \
    { const float dx = uxA-(KX), dy = uyA-(KY), dz = uzA-(KZ); \
      const float d = __fadd_rn(__fadd_rn(__fmul_rn(dx,dx),__fmul_rn(dy,dy)),__fmul_rn(dz,dz)); \
      INS(d, MI, dA0,iA0,dA1,iA1,dA2,iA2) } \
    { const float dx = uxB-(KX), dy = uyB-(KY), dz = uzB-(KZ); \
      const float d = __fadd_rn(__fadd_rn(__fmul_rn(dx,dx),__fmul_rn(dy,dy)),__fmul_rn(dz,dz)); \
      INS(d, MI, dB0,iB0,dB1,iB1,dB2,iB2) } }

__global__ __launch_bounds__(NTH) void fp_interp_kernel(
    const float* __restrict__ unknown,
    const float* __restrict__ known,
    const float* __restrict__ feats,
    float* __restrict__ out)
{
    __shared__ float kxs[MM];
    __shared__ float kys[MM];
    __shared__ float kzs[MM];
    __shared__ float pd[NCH][PTS][3];
    __shared__ int   pi[NCH][PTS][3];
    __shared__ float sw[3][PTS];
    __shared__ int   si[3][PTS];

    const int tilesPerBatch = NN / PTS;   // 64
    const int b    = blockIdx.x / tilesPerBatch;
    const int tile = blockIdx.x % tilesPerBatch;
    const int t    = threadIdx.x;
    const int p    = t & 63;              // lane = point pair id
    const int g    = t >> 6;              // wave id == chunk id (uniform/wave)

    // Stage known[b] (AoS) into SoA LDS. Coalesced global reads; branchless
    // scatter via pointer select (cndmask, no divergence).
    const float* kb = known + (size_t)b * MM * 3;
    for (int idx = t; idx < MM * 3; idx += NTH) {
        const float v  = kb[idx];
        const int   a  = idx % 3;
        const int   mi = idx / 3;
        float* dst = (a == 0) ? kxs : ((a == 1) ? kys : kzs);
        dst[mi] = v;
    }
    __syncthreads();

    // Two unknown points per thread: nA = tile*128 + p, nB = nA + 64.
    const float* uA = unknown + ((size_t)b * NN + (size_t)tile * PTS + p) * 3;
    const float uxA = uA[0], uyA = uA[1], uzA = uA[2];
    const float* uB = uA + 64 * 3;
    const float uxB = uB[0], uyB = uB[1], uzB = uB[2];

    float dA0=1e30f, dA1=1e30f, dA2=1e30f; int iA0=0, iA1=0, iA2=0;
    float dB0=1e30f, dB1=1e30f, dB2=1e30f; int iB0=0, iB1=0, iB2=0;

    const int mbeg = g * CHUNK;
    #pragma unroll 2
    for (int m = mbeg; m < mbeg + CHUNK; m += 4) {
        // Wave-uniform addresses -> broadcast ds_read_b128, conflict-free.
        const float4 x4 = *reinterpret_cast<const float4*>(&kxs[m]);
        const float4 y4 = *reinterpret_cast<const float4*>(&kys[m]);
        const float4 z4 = *reinterpret_cast<const float4*>(&kzs[m]);
        STEP(x4.x, y4.x, z4.x, m)
        STEP(x4.y, y4.y, z4.y, m+1)
        STEP(x4.z, y4.z, z4.z, m+2)
        STEP(x4.w, y4.w, z4.w, m+3)
    }

    pd[g][p][0] = dA0; pd[g][p][1] = dA1; pd[g][p][2] = dA2;
    pi[g][p][0] = iA0; pi[g][p][1] = iA1; pi[g][p][2] = iA2;
    pd[g][p+64][0] = dB0; pd[g][p+64][1] = dB1; pd[g][p+64][2] = dB2;
    pi[g][p+64][0] = iB0; pi[g][p+64][1] = iB1; pi[g][p+64][2] = iB2;
    __syncthreads();

    // Merge 8 sorted partial lists per point. Insertion order =
    // (chunk asc, rank asc) = ascending index for equal d -> stable.
    if (t < PTS) {
        float e0=1e30f, e1=1e30f, e2=1e30f; int j0=0, j1=0, j2=0;
        #pragma unroll
        for (int q = 0; q < NCH; ++q) {
            #pragma unroll
            for (int r = 0; r < 3; ++r) {
                const float d  = pd[q][t][r];
                const int   ii = pi[q][t][r];
                INS(d, ii, e0,j0,e1,j1,e2,j2)
            }
        }
        const float r0 = 1.0f / (e0 + EPSV);
        const float r1 = 1.0f / (e1 + EPSV);
        const float r2 = 1.0f / (e2 + EPSV);
        const float rs = r0 + r1 + r2;
        sw[0][t] = r0 / rs; sw[1][t] = r1 / rs; sw[2][t] = r2 / rs;
        si[0][t] = j0;      si[1][t] = j1;      si[2][t] = j2;
    }
    __syncthreads();

    // Interpolate: out[b][c][n] = sum_k w_k * F[b][c][i_k].
    // cg = t>>7 in 0..3 handles channels c = cg, cg+4, ...; stores are
    // 64-lane contiguous 256B per wave.
    const int pp = t & 127;
    const int cg = t >> 7;
    const float w0 = sw[0][pp], w1 = sw[1][pp], w2 = sw[2][pp];
    const int   j0 = si[0][pp], j1 = si[1][pp], j2 = si[2][pp];
    const float* fb = feats + (size_t)b * CC * MM;
    float* ob = out + (size_t)b * CC * NN + (size_t)tile * PTS;

    #pragma unroll 4
    for (int c = cg; c < CC; c += 4) {
        const float* fr = fb + (size_t)c * MM;
        ob[(size_t)c * NN + pp] = w0 * fr[j0] + w1 * fr[j1] + w2 * fr[j2];
    }
}

extern "C" void kernel_launch(void* const* d_in, const int* in_sizes, int n_in,
                              void* d_out, int out_size, void* d_ws, size_t ws_size,
                              hipStream_t stream) {
    const float* unknown = (const float*)d_in[0];
    const float* known   = (const float*)d_in[1];
    const float* feats   = (const float*)d_in[2];
    float* out = (float*)d_out;

    const int nBlocks = BB * (NN / PTS);  // 512
    fp_interp_kernel<<<nBlocks, NTH, 0, stream>>>(unknown, known, feats, out);
}

// Round 4
// 183.526 us; speedup vs baseline: 2.0483x; 1.0592x over previous
//
#include <hip/hip_runtime.h>

// PointnetFPModule: three_nn (brute force, top-3 smallest d2) + three_interpolate.
// Shapes: B=8, N=8192, M=2048, C=256.  All fp32.
// unknown (B,N,3), known (B,M,3), known_feats (B,C,M) -> out (B,C,N)
//
// R4: the branchy top-3 insert executed on ~95% of candidates at wave
// granularity (fresh list per chunk) -> SALU/exec-mask serialization.
// Replace with branch-free insert: distances via v_min/v_med3 (sorted-list
// identity), indices via 3 v_cmp + 5 v_cndmask off the OLD list. 19 VALU
// ops per (point,candidate) total, no branches in the hot loop.

#define BB 8
#define NN 8192
#define MM 2048
#define CC 256
#define EPSV 1e-8f
#define PTS 128          // points per block (64 lanes x 2 points/thread)
#define NTH 512          // threads per block = 8 waves
#define NCH 8            // chunks = waves (chunk id wave-uniform!)
#define CHUNK (MM/NCH)   // 256

// Branchy stable insert (merge phase only; tiny candidate count there).
#define INS(dd, mi, D0,I0,D1,I1,D2,I2) \
    if ((dd) < D2) { \
        if ((dd) < D1) { D2 = D1; I2 = I1; \
            if ((dd) < D0) { D1 = D0; I1 = I0; D0 = (dd); I0 = (mi); } \
            else           { D1 = (dd); I1 = (mi); } \
        } else { D2 = (dd); I2 = (mi); } }

// Branch-free stable insert. Requires D0<=D1<=D2 invariant (holds from init).
// Strict < on old values => ascending-index arrival preserves top_k stability.
#define PINS(dd, mi, D0,I0,D1,I1,D2,I2) { \
    const bool c0 = (dd) < D0, c1 = (dd) < D1, c2 = (dd) < D2; \
    I2 = c1 ? I1 : (c2 ? (mi) : I2); \
    I1 = c0 ? I0 : (c1 ? (mi) : I1); \
    I0 = c0 ? (mi) : I0; \
    D2 = __builtin_amdgcn_fmed3f(D1, D2, (dd)); \
    D1 = __builtin_amdgcn_fmed3f(D0, D1, (dd)); \
    D0 = fminf(D0, (dd)); }

// One known point vs both unknown points. Match numpy exactly: no FMA
// contraction, sum order (x^2 + y^2) + z^2.
#define STEP(KX,KY,KZ,MI) { \
    { const float dx = uxA-(KX), dy = uyA-(KY), dz = uzA-(KZ); \
      const float d = __fadd_rn(__fadd_rn(__fmul_rn(dx,dx),__fmul_rn(dy,dy)),__fmul_rn(dz,dz)); \
      PINS(d, MI, dA0,iA0,dA1,iA1,dA2,iA2) } \
    { const float dx = uxB-(KX), dy = uyB-(KY), dz = uzB-(KZ); \
      const float d = __fadd_rn(__fadd_rn(__fmul_rn(dx,dx),__fmul_rn(dy,dy)),__fmul_rn(dz,dz)); \
      PINS(d, MI, dB0,iB0,dB1,iB1,dB2,iB2) } }

__global__ __launch_bounds__(NTH) void fp_interp_kernel(
    const float* __restrict__ unknown,
    const float* __restrict__ known,
    const float* __restrict__ feats,
    float* __restrict__ out)
{
    __shared__ float kxs[MM];
    __shared__ float kys[MM];
    __shared__ float kzs[MM];
    __shared__ float pd[NCH][PTS][3];
    __shared__ int   pi[NCH][PTS][3];
    __shared__ float sw[3][PTS];
    __shared__ int   si[3][PTS];

    const int tilesPerBatch = NN / PTS;   // 64
    const int b    = blockIdx.x / tilesPerBatch;
    const int tile = blockIdx.x % tilesPerBatch;
    const int t    = threadIdx.x;
    const int p    = t & 63;              // lane = point pair id
    const int g    = t >> 6;              // wave id == chunk id (uniform/wave)

    // Stage known[b] (AoS) into SoA LDS.
    const float* kb = known + (size_t)b * MM * 3;
    for (int idx = t; idx < MM * 3; idx += NTH) {
        const float v  = kb[idx];
        const int   a  = idx % 3;
        const int   mi = idx / 3;
        float* dst = (a == 0) ? kxs : ((a == 1) ? kys : kzs);
        dst[mi] = v;
    }
    __syncthreads();

    // Two unknown points per thread: nA = tile*128 + p, nB = nA + 64.
    const float* uA = unknown + ((size_t)b * NN + (size_t)tile * PTS + p) * 3;
    const float uxA = uA[0], uyA = uA[1], uzA = uA[2];
    const float* uB = uA + 64 * 3;
    const float uxB = uB[0], uyB = uB[1], uzB = uB[2];

    float dA0=1e30f, dA1=1e30f, dA2=1e30f; int iA0=0, iA1=0, iA2=0;
    float dB0=1e30f, dB1=1e30f, dB2=1e30f; int iB0=0, iB1=0, iB2=0;

    const int mbeg = g * CHUNK;
    #pragma unroll 2
    for (int m = mbeg; m < mbeg + CHUNK; m += 4) {
        // Wave-uniform addresses -> broadcast ds_read_b128, conflict-free.
        const float4 x4 = *reinterpret_cast<const float4*>(&kxs[m]);
        const float4 y4 = *reinterpret_cast<const float4*>(&kys[m]);
        const float4 z4 = *reinterpret_cast<const float4*>(&kzs[m]);
        STEP(x4.x, y4.x, z4.x, m)
        STEP(x4.y, y4.y, z4.y, m+1)
        STEP(x4.z, y4.z, z4.z, m+2)
        STEP(x4.w, y4.w, z4.w, m+3)
    }

    pd[g][p][0] = dA0; pd[g][p][1] = dA1; pd[g][p][2] = dA2;
    pi[g][p][0] = iA0; pi[g][p][1] = iA1; pi[g][p][2] = iA2;
    pd[g][p+64][0] = dB0; pd[g][p+64][1] = dB1; pd[g][p+64][2] = dB2;
    pi[g][p+64][0] = iB0; pi[g][p+64][1] = iB1; pi[g][p+64][2] = iB2;
    __syncthreads();

    // Merge 8 sorted partial lists per point. Insertion order =
    // (chunk asc, rank asc) = ascending index for equal d -> stable.
    if (t < PTS) {
        float e0=1e30f, e1=1e30f, e2=1e30f; int j0=0, j1=0, j2=0;
        #pragma unroll
        for (int q = 0; q < NCH; ++q) {
            #pragma unroll
            for (int r = 0; r < 3; ++r) {
                const float d  = pd[q][t][r];
                const int   ii = pi[q][t][r];
                INS(d, ii, e0,j0,e1,j1,e2,j2)
            }
        }
        const float r0 = 1.0f / (e0 + EPSV);
        const float r1 = 1.0f / (e1 + EPSV);
        const float r2 = 1.0f / (e2 + EPSV);
        const float rs = r0 + r1 + r2;
        sw[0][t] = r0 / rs; sw[1][t] = r1 / rs; sw[2][t] = r2 / rs;
        si[0][t] = j0;      si[1][t] = j1;      si[2][t] = j2;
    }
    __syncthreads();

    // Interpolate: out[b][c][n] = sum_k w_k * F[b][c][i_k].
    // cg = t>>7 in 0..3 handles channels c = cg, cg+4, ...; stores are
    // 64-lane contiguous 256B per wave.
    const int pp = t & 127;
    const int cg = t >> 7;
    const float w0 = sw[0][pp], w1 = sw[1][pp], w2 = sw[2][pp];
    const int   j0 = si[0][pp], j1 = si[1][pp], j2 = si[2][pp];
    const float* fb = feats + (size_t)b * CC * MM;
    float* ob = out + (size_t)b * CC * NN + (size_t)tile * PTS;

    #pragma unroll 4
    for (int c = cg; c < CC; c += 4) {
        const float* fr = fb + (size_t)c * MM;
        ob[(size_t)c * NN + pp] = w0 * fr[j0] + w1 * fr[j1] + w2 * fr[j2];
    }
}

extern "C" void kernel_launch(void* const* d_in, const int* in_sizes, int n_in,
                              void* d_out, int out_size, void* d_ws, size_t ws_size,
                              hipStream_t stream) {
    const float* unknown = (const float*)d_in[0];
    const float* known   = (const float*)d_in[1];
    const float* feats   = (const float*)d_in[2];
    float* out = (float*)d_out;

    const int nBlocks = BB * (NN / PTS);  // 512
    fp_interp_kernel<<<nBlocks, NTH, 0, stream>>>(unknown, known, feats, out);
}

// Round 6
// 151.761 us; speedup vs baseline: 2.4771x; 1.2093x over previous
//
#include <hip/hip_runtime.h>

// PointnetFPModule: three_nn (brute force, top-3 smallest d2) + three_interpolate.
// Shapes: B=8, N=8192, M=2048, C=256.  All fp32.
// unknown (B,N,3), known (B,M,3), known_feats (B,C,M) -> out (B,C,N)
//
// R5 (resubmit; R5 bench was a broker timeout): interp gathers were
// texture-pipe line-divergence bound (~50 distinct 64B lines per 64-lane
// gather => ~65-80us). Split into two kernels:
//   k1 scan: top-3 + weights -> d_ws (float4 + int4 per point, 2MB)
//   k2 interp: per (b, 4-channel tile) block stages 32KB of feats in LDS
//      (coalesced, feats read from HBM exactly once), gathers from LDS
//      (~6-10 cyc random-bank reads vs ~50 cyc line-divergent L1).

#define BB 8
#define NN 8192
#define MM 2048
#define CC 256
#define EPSV 1e-8f
#define PTS 128          // points per scan block (64 lanes x 2 points/thread)
#define NTH 512          // threads per block = 8 waves
#define NCH 8            // chunks = waves (chunk id wave-uniform!)
#define CHUNK (MM/NCH)   // 256
#define TC 4             // channels per interp block

// Branchy stable insert (merge phase only; tiny candidate count there).
#define INS(dd, mi, D0,I0,D1,I1,D2,I2) \
    if ((dd) < D2) { \
        if ((dd) < D1) { D2 = D1; I2 = I1; \
            if ((dd) < D0) { D1 = D0; I1 = I0; D0 = (dd); I0 = (mi); } \
            else           { D1 = (dd); I1 = (mi); } \
        } else { D2 = (dd); I2 = (mi); } }

// Branch-free stable insert. Requires D0<=D1<=D2 invariant (holds from init).
// Strict < on old values => ascending-index arrival preserves top_k stability.
#define PINS(dd, mi, D0,I0,D1,I1,D2,I2) { \
    const bool c0 = (dd) < D0, c1 = (dd) < D1, c2 = (dd) < D2; \
    I2 = c1 ? I1 : (c2 ? (mi) : I2); \
    I1 = c0 ? I0 : (c1 ? (mi) : I1); \
    I0 = c0 ? (mi) : I0; \
    D2 = __builtin_amdgcn_fmed3f(D1, D2, (dd)); \
    D1 = __builtin_amdgcn_fmed3f(D0, D1, (dd)); \
    D0 = fminf(D0, (dd)); }

// One known point vs both unknown points. Match numpy exactly: no FMA
// contraction, sum order (x^2 + y^2) + z^2.
#define STEP(KX,KY,KZ,MI) { \
    { const float dx = uxA-(KX), dy = uyA-(KY), dz = uzA-(KZ); \
      const float d = __fadd_rn(__fadd_rn(__fmul_rn(dx,dx),__fmul_rn(dy,dy)),__fmul_rn(dz,dz)); \
      PINS(d, MI, dA0,iA0,dA1,iA1,dA2,iA2) } \
    { const float dx = uxB-(KX), dy = uyB-(KY), dz = uzB-(KZ); \
      const float d = __fadd_rn(__fadd_rn(__fmul_rn(dx,dx),__fmul_rn(dy,dy)),__fmul_rn(dz,dz)); \
      PINS(d, MI, dB0,iB0,dB1,iB1,dB2,iB2) } }

__global__ __launch_bounds__(NTH) void nn_scan_kernel(
    const float* __restrict__ unknown,
    const float* __restrict__ known,
    float4* __restrict__ wgt4,
    int4*  __restrict__ idx4)
{
    __shared__ float kxs[MM];
    __shared__ float kys[MM];
    __shared__ float kzs[MM];
    __shared__ float pd[NCH][PTS][3];
    __shared__ int   pi[NCH][PTS][3];

    const int tilesPerBatch = NN / PTS;   // 64
    const int b    = blockIdx.x / tilesPerBatch;
    const int tile = blockIdx.x % tilesPerBatch;
    const int t    = threadIdx.x;
    const int p    = t & 63;              // lane = point pair id
    const int g    = t >> 6;              // wave id == chunk id (uniform/wave)

    // Stage known[b] (AoS) into SoA LDS.
    const float* kb = known + (size_t)b * MM * 3;
    for (int idx = t; idx < MM * 3; idx += NTH) {
        const float v  = kb[idx];
        const int   a  = idx % 3;
        const int   mi = idx / 3;
        float* dst = (a == 0) ? kxs : ((a == 1) ? kys : kzs);
        dst[mi] = v;
    }
    __syncthreads();

    // Two unknown points per thread: nA = tile*128 + p, nB = nA + 64.
    const float* uA = unknown + ((size_t)b * NN + (size_t)tile * PTS + p) * 3;
    const float uxA = uA[0], uyA = uA[1], uzA = uA[2];
    const float* uB = uA + 64 * 3;
    const float uxB = uB[0], uyB = uB[1], uzB = uB[2];

    float dA0=1e30f, dA1=1e30f, dA2=1e30f; int iA0=0, iA1=0, iA2=0;
    float dB0=1e30f, dB1=1e30f, dB2=1e30f; int iB0=0, iB1=0, iB2=0;

    const int mbeg = g * CHUNK;
    #pragma unroll 2
    for (int m = mbeg; m < mbeg + CHUNK; m += 4) {
        // Wave-uniform addresses -> broadcast ds_read_b128, conflict-free.
        const float4 x4 = *reinterpret_cast<const float4*>(&kxs[m]);
        const float4 y4 = *reinterpret_cast<const float4*>(&kys[m]);
        const float4 z4 = *reinterpret_cast<const float4*>(&kzs[m]);
        STEP(x4.x, y4.x, z4.x, m)
        STEP(x4.y, y4.y, z4.y, m+1)
        STEP(x4.z, y4.z, z4.z, m+2)
        STEP(x4.w, y4.w, z4.w, m+3)
    }

    pd[g][p][0] = dA0; pd[g][p][1] = dA1; pd[g][p][2] = dA2;
    pi[g][p][0] = iA0; pi[g][p][1] = iA1; pi[g][p][2] = iA2;
    pd[g][p+64][0] = dB0; pd[g][p+64][1] = dB1; pd[g][p+64][2] = dB2;
    pi[g][p+64][0] = iB0; pi[g][p+64][1] = iB1; pi[g][p+64][2] = iB2;
    __syncthreads();

    // Merge 8 sorted partial lists per point. Insertion order =
    // (chunk asc, rank asc) = ascending index for equal d -> stable.
    if (t < PTS) {
        float e0=1e30f, e1=1e30f, e2=1e30f; int j0=0, j1=0, j2=0;
        #pragma unroll
        for (int q = 0; q < NCH; ++q) {
            #pragma unroll
            for (int r = 0; r < 3; ++r) {
                const float d  = pd[q][t][r];
                const int   ii = pi[q][t][r];
                INS(d, ii, e0,j0,e1,j1,e2,j2)
            }
        }
        const float r0 = 1.0f / (e0 + EPSV);
        const float r1 = 1.0f / (e1 + EPSV);
        const float r2 = 1.0f / (e2 + EPSV);
        const float rs = r0 + r1 + r2;
        const int gp = b * NN + tile * PTS + t;
        wgt4[gp] = make_float4(r0 / rs, r1 / rs, r2 / rs, 0.0f);
        idx4[gp] = make_int4(j0, j1, j2, 0);
    }
}

__global__ __launch_bounds__(NTH) void interp_kernel(
    const float* __restrict__ feats,
    const float4* __restrict__ wgt4,
    const int4*  __restrict__ idx4,
    float* __restrict__ out)
{
    __shared__ float fbuf[TC * MM];       // 32 KB

    const int tilesPerB = CC / TC;        // 64
    const int b  = blockIdx.x / tilesPerB;
    const int c0 = (blockIdx.x % tilesPerB) * TC;
    const int t  = threadIdx.x;

    // Stage 4 contiguous feature rows (32KB linear) into LDS. Coalesced;
    // feats is read from HBM exactly once across the grid.
    const float4* src = reinterpret_cast<const float4*>(
        feats + ((size_t)b * CC + c0) * MM);
    #pragma unroll
    for (int i = t; i < TC * MM / 4; i += NTH)
        reinterpret_cast<float4*>(fbuf)[i] = src[i];
    __syncthreads();

    // 8192 points / 512 threads = 16 iterations.
    #pragma unroll 2
    for (int it = 0; it < NN / NTH; ++it) {
        const int n = it * NTH + t;
        const float4 w = wgt4[b * NN + n];
        const int4   j = idx4[b * NN + n];
        float* ob = out + ((size_t)b * CC + c0) * NN + n;
        #pragma unroll
        for (int cl = 0; cl < TC; ++cl) {
            const float* fr = fbuf + cl * MM;
            ob[(size_t)cl * NN] = w.x * fr[j.x] + w.y * fr[j.y] + w.z * fr[j.z];
        }
    }
}

extern "C" void kernel_launch(void* const* d_in, const int* in_sizes, int n_in,
                              void* d_out, int out_size, void* d_ws, size_t ws_size,
                              hipStream_t stream) {
    const float* unknown = (const float*)d_in[0];
    const float* known   = (const float*)d_in[1];
    const float* feats   = (const float*)d_in[2];
    float* out = (float*)d_out;

    float4* wgt4 = (float4*)d_ws;                       // 65536 * 16B = 1MB
    int4*   idx4 = (int4*)((char*)d_ws + (size_t)BB * NN * sizeof(float4));

    nn_scan_kernel<<<BB * (NN / PTS), NTH, 0, stream>>>(unknown, known, wgt4, idx4);
    interp_kernel<<<BB * (CC / TC), NTH, 0, stream>>>(feats, wgt4, idx4, out);
}